// Round 12
// baseline (201.735 us; speedup 1.0000x reference)
//
#include <hip/hip_runtime.h>
#include <math.h>

#define NB 32
#define LQ 2048
#define LK 2048
#define HD 1024
#define AD 512
#define QCH 32   // q-chunks for first-stage query reduction (1024 stream blocks)

// =====================================================================
// K1: blocks 0..255    : MT tile GEMM  MT[h][h'] = Wk[h,:]·Wq[h',:]
//                        (+ aux: wv_eff, ck on pb==0 blocks; c_v on block 0)
//     blocks 256..1279 : query partial-reduce (streaming, 4 rows in flight)
//     blocks 1280..1295: (folded into pb==0 aux above — none here)
// MT blocks first so their VALU work hides under the memory-bound stream.
// (MT path numerically verified in round 7: absmax 0)
// =====================================================================
__global__ void __launch_bounds__(256, 4)
k1_main(const float* __restrict__ query, const float* __restrict__ Wq,
        const float* __restrict__ Wk, const float* __restrict__ Wv,
        const float* __restrict__ bq, const float* __restrict__ bk,
        const float* __restrict__ bv, float* __restrict__ partial,
        float* __restrict__ MT, float* __restrict__ wv_eff,
        float* __restrict__ ck, float* __restrict__ c_v) {
    __shared__ float wq_l[128][33];
    __shared__ float wk_l[32][33];
    const int bid = blockIdx.x;
    const int t = threadIdx.x;

    if (bid >= 256) {
        // ---- streaming: partial[qc][b][h] = sum over 64-row q-chunk ----
        int task = bid - 256;
        int b = task / QCH, qc = task % QCH;
        const int QPC = LQ / QCH;        // 64 rows
        float4 a0 = {0.f,0.f,0.f,0.f}, a1 = {0.f,0.f,0.f,0.f};
        float4 a2 = {0.f,0.f,0.f,0.f}, a3 = {0.f,0.f,0.f,0.f};
        const float4* src = (const float4*)(query + ((size_t)b * LQ + (size_t)qc * QPC) * HD);
        for (int q = 0; q < QPC; q += 4) {
            float4 v0 = src[(size_t)(q + 0) * (HD / 4) + t];
            float4 v1 = src[(size_t)(q + 1) * (HD / 4) + t];
            float4 v2 = src[(size_t)(q + 2) * (HD / 4) + t];
            float4 v3 = src[(size_t)(q + 3) * (HD / 4) + t];
            a0.x += v0.x; a0.y += v0.y; a0.z += v0.z; a0.w += v0.w;
            a1.x += v1.x; a1.y += v1.y; a1.z += v1.z; a1.w += v1.w;
            a2.x += v2.x; a2.y += v2.y; a2.z += v2.z; a2.w += v2.w;
            a3.x += v3.x; a3.y += v3.y; a3.z += v3.z; a3.w += v3.w;
        }
        float4 acc = {(a0.x + a1.x) + (a2.x + a3.x), (a0.y + a1.y) + (a2.y + a3.y),
                      (a0.z + a1.z) + (a2.z + a3.z), (a0.w + a1.w) + (a2.w + a3.w)};
        ((float4*)(partial + ((size_t)qc * NB + b) * HD))[t] = acc;
        return;
    }

    // ---- MT tile GEMM: tile = 32 h-rows x 128 h'-cols, K = 512 ----
    const int hb = bid >> 3;             // 0..31 -> h0 = hb*32
    const int pb = bid & 7;              // 0..7  -> h'0 = pb*128
    const int hgrp = t >> 5;             // 0..7
    const int pgrp = t & 31;             // 0..31
    float acc[4][4] = {{0.f}};
    for (int ac = 0; ac < 16; ++ac) {    // 16 chunks of 32 a
        for (int s = t; s < 128 * 32; s += 256) {
            int row = s >> 5, a = s & 31;
            wq_l[row][a] = Wq[(size_t)(pb * 128 + row) * AD + ac * 32 + a];
        }
        for (int s = t; s < 32 * 32; s += 256) {
            int row = s >> 5, a = s & 31;
            wk_l[row][a] = Wk[(size_t)(hb * 32 + row) * AD + ac * 32 + a];
        }
        __syncthreads();
        #pragma unroll 8
        for (int a = 0; a < 32; ++a) {
            float k0 = wk_l[hgrp][a],      k1 = wk_l[hgrp + 8][a],
                  k2 = wk_l[hgrp + 16][a], k3 = wk_l[hgrp + 24][a];
            float q0 = wq_l[pgrp][a],      q1 = wq_l[pgrp + 32][a],
                  q2 = wq_l[pgrp + 64][a], q3 = wq_l[pgrp + 96][a];
            acc[0][0] += k0*q0; acc[0][1] += k0*q1; acc[0][2] += k0*q2; acc[0][3] += k0*q3;
            acc[1][0] += k1*q0; acc[1][1] += k1*q1; acc[1][2] += k1*q2; acc[1][3] += k1*q3;
            acc[2][0] += k2*q0; acc[2][1] += k2*q1; acc[2][2] += k2*q2; acc[2][3] += k2*q3;
            acc[3][0] += k3*q0; acc[3][1] += k3*q1; acc[3][2] += k3*q2; acc[3][3] += k3*q3;
        }
        __syncthreads();
    }
    #pragma unroll
    for (int i = 0; i < 4; ++i)
        #pragma unroll
        for (int j = 0; j < 4; ++j)
            MT[(size_t)(hb * 32 + hgrp + 8 * i) * HD + pb * 128 + pgrp + 32 * j] = acc[i][j];

    // ---- aux on pb==0 blocks: wv_eff[h] = Wk[h,:]·Wv ; ck[h] = LQ*(bq·Wk[h,:]) ----
    if (pb == 0) {
        int w = t >> 6, lane = t & 63;
        const float4* vv4 = (const float4*)Wv;
        const float4* bq4 = (const float4*)bq;
        for (int rr = 0; rr < 8; ++rr) {
            int h = hb * 32 + w * 8 + rr;
            const float4* wr = (const float4*)(Wk + (size_t)h * AD);
            double a1 = 0.0, a2 = 0.0;
            #pragma unroll
            for (int j = 0; j < 2; ++j) {
                int f = lane + 64 * j;
                float4 w4 = wr[f];
                float4 v4 = vv4[f];
                float4 b4 = bq4[f];
                a1 += (double)w4.x * v4.x + (double)w4.y * v4.y
                    + (double)w4.z * v4.z + (double)w4.w * v4.w;
                a2 += (double)b4.x * w4.x + (double)b4.y * w4.y
                    + (double)b4.z * w4.z + (double)b4.w * w4.w;
            }
            #pragma unroll
            for (int off = 32; off > 0; off >>= 1) {
                a1 += __shfl_down(a1, off);
                a2 += __shfl_down(a2, off);
            }
            if (lane == 0) {
                wv_eff[h] = (float)a1;
                ck[h] = (float)((double)LQ * a2);
            }
        }
    }
    if (bid == 0 && t < 64) {
        int lane = t;
        const float4* br = (const float4*)bk;
        const float4* vv4 = (const float4*)Wv;
        double acc2 = 0.0;
        #pragma unroll
        for (int j = 0; j < 2; ++j) {
            int f = lane + 64 * j;
            float4 b4 = br[f];
            float4 v4 = vv4[f];
            acc2 += (double)b4.x * v4.x + (double)b4.y * v4.y
                  + (double)b4.z * v4.z + (double)b4.w * v4.w;
        }
        #pragma unroll
        for (int off = 32; off > 0; off >>= 1) acc2 += __shfl_down(acc2, off);
        if (lane == 0) c_v[0] = (float)(acc2 + (double)bv[0]);
    }
}

// =====================================================================
// K2: 256 blocks (b = bid>>3, h-chunk = bid&7):
//   stage s_q[b] in LDS (reduce partial), then
//   wk_eff[b][h] = s_q[b]·MT[h,:] + ck[h]   (wave-per-row)
// (round-7 verified code, minus counter init)
// =====================================================================
__global__ void __launch_bounds__(256)
k2_wkeff(const float* __restrict__ partial, const float* __restrict__ MT,
         const float* __restrict__ ck, float* __restrict__ wk_eff) {
    __shared__ float sq[HD];
    const int bid = blockIdx.x;
    const int t = threadIdx.x;
    const int b = bid >> 3, hc = bid & 7;
    for (int h = t; h < HD; h += 256) {
        float acc = 0.f;
        #pragma unroll 4
        for (int qc = 0; qc < QCH; ++qc)
            acc += partial[((size_t)qc * NB + b) * HD + h];
        sq[h] = acc;
    }
    __syncthreads();
    int w = t >> 6, lane = t & 63;
    const float4* sq4 = (const float4*)sq;
    for (int rr = 0; rr < 32; ++rr) {
        int h = hc * 128 + w * 32 + rr;
        const float4* m4 = (const float4*)(MT + (size_t)h * HD);
        double acc = 0.0;
        #pragma unroll
        for (int f0 = 0; f0 < 4; ++f0) {
            int f = lane + 64 * f0;
            float4 m = m4[f];
            float4 s = sq4[f];
            acc += (double)m.x * s.x + (double)m.y * s.y
                 + (double)m.z * s.z + (double)m.w * s.w;
        }
        #pragma unroll
        for (int off = 32; off > 0; off >>= 1) acc += __shfl_down(acc, off);
        if (lane == 0) wk_eff[(size_t)b * HD + h] = (float)(acc + (double)ck[h]);
    }
}

// =====================================================================
// K4: 2048 blocks, 32 keys each, 4 rows in flight (round-9 proven):
//   scores = key·wk_eff[b], vvals = key·wv_eff + c_v
// =====================================================================
__global__ void __launch_bounds__(256)
k4_scores(const float* __restrict__ key, const float* __restrict__ wk_eff,
          const float* __restrict__ wv_eff, const float* __restrict__ c_v,
          float* __restrict__ scores, float* __restrict__ vvals) {
    __shared__ float lwk[HD];
    __shared__ float lwv[HD];
    const int bid = blockIdx.x;
    const int b = bid >> 6;              // 64 blocks per batch
    const int k0 = (bid & 63) * 32;
    const int t = threadIdx.x;
    for (int i = t; i < HD; i += 256) {
        lwk[i] = wk_eff[(size_t)b * HD + i];
        lwv[i] = wv_eff[i];
    }
    __syncthreads();
    int w = t >> 6, lane = t & 63;
    double cv = (double)c_v[0];
    const float4* lwk4 = (const float4*)lwk;
    const float4* lwv4 = (const float4*)lwv;
    for (int rp = 0; rp < 2; ++rp) {
        int k = k0 + w * 8 + rp * 4;
        const float4* kr0 = (const float4*)(key + ((size_t)b * LK + k) * HD);
        const float4* kr1 = kr0 + (HD / 4);
        const float4* kr2 = kr0 + 2 * (HD / 4);
        const float4* kr3 = kr0 + 3 * (HD / 4);
        double sc0 = 0.0, vv0 = 0.0, sc1 = 0.0, vv1 = 0.0;
        double sc2 = 0.0, vv2 = 0.0, sc3 = 0.0, vv3 = 0.0;
        #pragma unroll
        for (int j = 0; j < 4; ++j) {
            int f = lane + 64 * j;
            float4 k0v = kr0[f];
            float4 k1v = kr1[f];
            float4 k2v = kr2[f];
            float4 k3v = kr3[f];
            float4 wk4 = lwk4[f];
            float4 wv4 = lwv4[f];
            sc0 += (double)k0v.x * wk4.x + (double)k0v.y * wk4.y
                 + (double)k0v.z * wk4.z + (double)k0v.w * wk4.w;
            vv0 += (double)k0v.x * wv4.x + (double)k0v.y * wv4.y
                 + (double)k0v.z * wv4.z + (double)k0v.w * wv4.w;
            sc1 += (double)k1v.x * wk4.x + (double)k1v.y * wk4.y
                 + (double)k1v.z * wk4.z + (double)k1v.w * wk4.w;
            vv1 += (double)k1v.x * wv4.x + (double)k1v.y * wv4.y
                 + (double)k1v.z * wv4.z + (double)k1v.w * wv4.w;
            sc2 += (double)k2v.x * wk4.x + (double)k2v.y * wk4.y
                 + (double)k2v.z * wk4.z + (double)k2v.w * wk4.w;
            vv2 += (double)k2v.x * wv4.x + (double)k2v.y * wv4.y
                 + (double)k2v.z * wv4.z + (double)k2v.w * wv4.w;
            sc3 += (double)k3v.x * wk4.x + (double)k3v.y * wk4.y
                 + (double)k3v.z * wk4.z + (double)k3v.w * wk4.w;
            vv3 += (double)k3v.x * wv4.x + (double)k3v.y * wv4.y
                 + (double)k3v.z * wv4.z + (double)k3v.w * wv4.w;
        }
        #pragma unroll
        for (int off = 32; off > 0; off >>= 1) {
            sc0 += __shfl_down(sc0, off);
            vv0 += __shfl_down(vv0, off);
            sc1 += __shfl_down(sc1, off);
            vv1 += __shfl_down(vv1, off);
            sc2 += __shfl_down(sc2, off);
            vv2 += __shfl_down(vv2, off);
            sc3 += __shfl_down(sc3, off);
            vv3 += __shfl_down(vv3, off);
        }
        if (lane == 0) {
            size_t base = (size_t)b * LK + k;
            scores[base]     = (float)sc0;  vvals[base]     = (float)(vv0 + cv);
            scores[base + 1] = (float)sc1;  vvals[base + 1] = (float)(vv1 + cv);
            scores[base + 2] = (float)sc2;  vvals[base + 2] = (float)(vv2 + cv);
            scores[base + 3] = (float)sc3;  vvals[base + 3] = (float)(vv3 + cv);
        }
    }
}

// =====================================================================
// K5: per-batch softmax + weighted sum -> out[b] (round-9 proven)
// =====================================================================
__global__ void __launch_bounds__(256)
k5_softmax(const float* __restrict__ scores, const float* __restrict__ vvals,
           float* __restrict__ out) {
    int b = blockIdx.x;
    int t = threadIdx.x;
    __shared__ float smax_sh[4];
    __shared__ double num_sh[4], den_sh[4];
    const float* sr = scores + (size_t)b * LK;
    const float* vr = vvals  + (size_t)b * LK;
    float m = -INFINITY;
    for (int k = t; k < LK; k += 256) m = fmaxf(m, sr[k]);
    #pragma unroll
    for (int off = 32; off > 0; off >>= 1) m = fmaxf(m, __shfl_down(m, off));
    int w = t >> 6, lane = t & 63;
    if (lane == 0) smax_sh[w] = m;
    __syncthreads();
    float gm = fmaxf(fmaxf(smax_sh[0], smax_sh[1]), fmaxf(smax_sh[2], smax_sh[3]));
    double num = 0.0, den = 0.0;
    for (int k = t; k < LK; k += 256) {
        double e = exp((double)(sr[k] - gm));
        den += e;
        num += e * (double)vr[k];
    }
    #pragma unroll
    for (int off = 32; off > 0; off >>= 1) {
        num += __shfl_down(num, off);
        den += __shfl_down(den, off);
    }
    if (lane == 0) { num_sh[w] = num; den_sh[w] = den; }
    __syncthreads();
    if (t == 0) {
        double N = num_sh[0] + num_sh[1] + num_sh[2] + num_sh[3];
        double D = den_sh[0] + den_sh[1] + den_sh[2] + den_sh[3];
        out[b] = (float)(N / D);
    }
}

extern "C" void kernel_launch(void* const* d_in, const int* in_sizes, int n_in,
                              void* d_out, int out_size, void* d_ws, size_t ws_size,
                              hipStream_t stream) {
    const float* query = (const float*)d_in[0];
    const float* key   = (const float*)d_in[1];
    const float* Wq    = (const float*)d_in[2];
    const float* bq    = (const float*)d_in[3];
    const float* Wk    = (const float*)d_in[4];
    const float* bk    = (const float*)d_in[5];
    const float* Wv    = (const float*)d_in[6];
    const float* bv    = (const float*)d_in[7];
    float* out = (float*)d_out;

    float* ws = (float*)d_ws;
    size_t off = 0;
    float* partial = ws + off; off += (size_t)QCH * NB * HD;   // 4 MB
    float* MT      = ws + off; off += (size_t)HD * HD;         // 4 MB
    float* wk_eff  = ws + off; off += (size_t)NB * HD;
    float* wv_eff  = ws + off; off += (size_t)HD;
    float* ck      = ws + off; off += (size_t)HD;
    float* c_v     = ws + off; off += 1;
    float* scores  = ws + off; off += (size_t)NB * LK;
    float* vvals   = ws + off; off += (size_t)NB * LK;

    hipLaunchKernelGGL(k1_main, dim3(256 + NB * QCH), dim3(256), 0, stream,
                       query, Wq, Wk, Wv, bq, bk, bv,
                       partial, MT, wv_eff, ck, c_v);
    hipLaunchKernelGGL(k2_wkeff, dim3(256), dim3(256), 0, stream,
                       partial, MT, ck, wk_eff);
    hipLaunchKernelGGL(k4_scores, dim3(NB * (LK / 32)), dim3(256), 0, stream,
                       key, wk_eff, wv_eff, c_v, scores, vvals);
    hipLaunchKernelGGL(k5_softmax, dim3(NB), dim3(256), 0, stream,
                       scores, vvals, out);
}

// Round 13
// 146.949 us; speedup vs baseline: 1.3728x; 1.3728x over previous
//
#include <hip/hip_runtime.h>
#include <math.h>

#define NB 32
#define LQ 2048
#define LK 2048
#define HD 1024
#define AD 512
#define QCH 64   // q-chunks for first-stage query reduction (2048 stream blocks)

typedef float vf4 __attribute__((ext_vector_type(4)));

// =====================================================================
// K1: blocks 0..2047   : partial[qc][b][h] = sum over 32-row q-chunk
//                        (4 rows in flight, non-temporal loads)
//     blocks 2048..2063: wv_eff[h] = Wk[h,:]·Wv (wave-per-row)
//     block  2064      : c_v = bk·Wv + bv
// =====================================================================
__global__ void __launch_bounds__(256)
k1_stream(const float* __restrict__ query, const float* __restrict__ Wk,
          const float* __restrict__ Wv, const float* __restrict__ bk,
          const float* __restrict__ bv, float* __restrict__ partial,
          float* __restrict__ wv_eff, float* __restrict__ c_v) {
    const int bid = blockIdx.x;
    const int t = threadIdx.x;
    if (bid < NB * QCH) {
        int b = bid / QCH, qc = bid % QCH;
        const int QPC = LQ / QCH;        // 32 rows per chunk
        vf4 a0 = {0.f,0.f,0.f,0.f}, a1 = {0.f,0.f,0.f,0.f};
        vf4 a2 = {0.f,0.f,0.f,0.f}, a3 = {0.f,0.f,0.f,0.f};
        const vf4* src = (const vf4*)(query + ((size_t)b * LQ + (size_t)qc * QPC) * HD);
        for (int q = 0; q < QPC; q += 4) {
            vf4 v0 = __builtin_nontemporal_load(&src[(size_t)(q + 0) * (HD / 4) + t]);
            vf4 v1 = __builtin_nontemporal_load(&src[(size_t)(q + 1) * (HD / 4) + t]);
            vf4 v2 = __builtin_nontemporal_load(&src[(size_t)(q + 2) * (HD / 4) + t]);
            vf4 v3 = __builtin_nontemporal_load(&src[(size_t)(q + 3) * (HD / 4) + t]);
            a0 += v0; a1 += v1; a2 += v2; a3 += v3;
        }
        vf4 acc = (a0 + a1) + (a2 + a3);
        ((vf4*)(partial + ((size_t)qc * NB + b) * HD))[t] = acc;
    } else if (bid < NB * QCH + 16) {
        int w = t >> 6, lane = t & 63;
        int gw = (bid - NB * QCH) * 4 + w;           // 0..63
        const float4* vv = (const float4*)Wv;
        for (int r = 0; r < 16; ++r) {
            int h = gw * 16 + r;
            const float4* wr = (const float4*)(Wk + (size_t)h * AD);
            double acc = 0.0;
            #pragma unroll
            for (int j = 0; j < 2; ++j) {
                int f = lane + 64 * j;               // covers AD/4 = 128
                float4 w4 = wr[f];
                float4 v4 = vv[f];
                acc += (double)w4.x * v4.x + (double)w4.y * v4.y
                     + (double)w4.z * v4.z + (double)w4.w * v4.w;
            }
            #pragma unroll
            for (int off = 32; off > 0; off >>= 1) acc += __shfl_down(acc, off);
            if (lane == 0) wv_eff[h] = (float)acc;
        }
    } else if (t < 64) {
        int lane = t;
        const float4* br = (const float4*)bk;
        const float4* vv = (const float4*)Wv;
        double acc = 0.0;
        #pragma unroll
        for (int j = 0; j < 2; ++j) {
            int f = lane + 64 * j;
            float4 b4 = br[f];
            float4 v4 = vv[f];
            acc += (double)b4.x * v4.x + (double)b4.y * v4.y
                 + (double)b4.z * v4.z + (double)b4.w * v4.w;
        }
        #pragma unroll
        for (int off = 32; off > 0; off >>= 1) acc += __shfl_down(acc, off);
        if (lane == 0) c_v[0] = (float)(acc + (double)bv[0]);
    }
}

// =====================================================================
// K2: 256 blocks: b = bid>>3, a-chunk of 64 = (bid&7)*64.
//   Phase A: s_q[b][:] into LDS; Phase B: qsum chunk. (proven round-3/9)
// =====================================================================
__global__ void __launch_bounds__(256)
k2_qsum(const float* __restrict__ partial, const float* __restrict__ Wq,
        const float* __restrict__ bq, float* __restrict__ qsum) {
    __shared__ float sq[HD];
    __shared__ double red[4][64];
    int b = blockIdx.x >> 3;
    int a0 = (blockIdx.x & 7) * 64;
    int t = threadIdx.x;

    #pragma unroll
    for (int c = 0; c < 4; ++c) {
        int h = t + c * 256;
        float acc = 0.f;
        #pragma unroll 4
        for (int qc = 0; qc < QCH; ++qc)
            acc += partial[((size_t)qc * NB + b) * HD + h];
        sq[h] = acc;
    }
    __syncthreads();

    int w = t >> 6, lane = t & 63;
    int a = a0 + lane;
    const float* wp = Wq + a;
    double c0 = 0.0, c1 = 0.0, c2 = 0.0, c3 = 0.0;
    int hbase = w * 256;
    for (int i = 0; i < 256; i += 4) {
        int h = hbase + i;
        c0 += (double)sq[h]     * wp[(size_t)h * AD];
        c1 += (double)sq[h + 1] * wp[(size_t)(h + 1) * AD];
        c2 += (double)sq[h + 2] * wp[(size_t)(h + 2) * AD];
        c3 += (double)sq[h + 3] * wp[(size_t)(h + 3) * AD];
    }
    red[w][lane] = ((c0 + c1) + (c2 + c3));
    __syncthreads();
    if (t < 64) {
        double s = red[0][t] + red[1][t] + red[2][t] + red[3][t];
        qsum[(size_t)b * AD + a0 + t] = (float)(s + (double)LQ * bq[a0 + t]);
    }
}

// =====================================================================
// K3: 2048 blocks x 4 waves, 4 rows per wave: wk_eff[b][h] = qsum[b]·Wk[h,:]
// (proven round-9)
// =====================================================================
__global__ void __launch_bounds__(256)
k3_weff(const float* __restrict__ qsum, const float* __restrict__ Wk,
        float* __restrict__ wk_eff) {
    int w = threadIdx.x >> 6, lane = threadIdx.x & 63;
    int widx = blockIdx.x * 4 + w;                   // 8192 waves
    int base = widx * 4;                             // 4 rows each
    for (int r = 0; r < 4; r += 2) {
        int idx0 = base + r;                         // 0..32767
        int b = idx0 >> 10, h0 = idx0 & (HD - 1);
        const float4* r0 = (const float4*)(Wk + (size_t)h0 * AD);
        const float4* r1 = (const float4*)(Wk + (size_t)(h0 + 1) * AD);
        const float4* qs = (const float4*)(qsum + (size_t)b * AD);
        double a0 = 0.0, a1 = 0.0;
        #pragma unroll
        for (int j = 0; j < 2; ++j) {
            int f = lane + 64 * j;
            float4 w0 = r0[f];
            float4 w1 = r1[f];
            float4 q4 = qs[f];
            a0 += (double)w0.x * q4.x + (double)w0.y * q4.y
                + (double)w0.z * q4.z + (double)w0.w * q4.w;
            a1 += (double)w1.x * q4.x + (double)w1.y * q4.y
                + (double)w1.z * q4.z + (double)w1.w * q4.w;
        }
        #pragma unroll
        for (int off = 32; off > 0; off >>= 1) {
            a0 += __shfl_down(a0, off);
            a1 += __shfl_down(a1, off);
        }
        if (lane == 0) {
            wk_eff[idx0]     = (float)a0;
            wk_eff[idx0 + 1] = (float)a1;
        }
    }
}

// =====================================================================
// K4: 2048 blocks, 32 keys each, 4 rows in flight, non-temporal key loads:
//   scores = key·wk_eff[b], vvals = key·wv_eff + c_v
// =====================================================================
__global__ void __launch_bounds__(256)
k4_scores(const float* __restrict__ key, const float* __restrict__ wk_eff,
          const float* __restrict__ wv_eff, const float* __restrict__ c_v,
          float* __restrict__ scores, float* __restrict__ vvals) {
    __shared__ float lwk[HD];
    __shared__ float lwv[HD];
    const int bid = blockIdx.x;
    const int b = bid >> 6;              // 64 blocks per batch
    const int k0 = (bid & 63) * 32;
    const int t = threadIdx.x;
    for (int i = t; i < HD; i += 256) {
        lwk[i] = wk_eff[(size_t)b * HD + i];
        lwv[i] = wv_eff[i];
    }
    __syncthreads();
    int w = t >> 6, lane = t & 63;
    double cv = (double)c_v[0];
    const vf4* lwk4 = (const vf4*)lwk;
    const vf4* lwv4 = (const vf4*)lwv;
    for (int rp = 0; rp < 2; ++rp) {
        int k = k0 + w * 8 + rp * 4;
        const vf4* kr0 = (const vf4*)(key + ((size_t)b * LK + k) * HD);
        const vf4* kr1 = kr0 + (HD / 4);
        const vf4* kr2 = kr0 + 2 * (HD / 4);
        const vf4* kr3 = kr0 + 3 * (HD / 4);
        double sc0 = 0.0, vv0 = 0.0, sc1 = 0.0, vv1 = 0.0;
        double sc2 = 0.0, vv2 = 0.0, sc3 = 0.0, vv3 = 0.0;
        #pragma unroll
        for (int j = 0; j < 4; ++j) {
            int f = lane + 64 * j;
            vf4 k0v = __builtin_nontemporal_load(&kr0[f]);
            vf4 k1v = __builtin_nontemporal_load(&kr1[f]);
            vf4 k2v = __builtin_nontemporal_load(&kr2[f]);
            vf4 k3v = __builtin_nontemporal_load(&kr3[f]);
            vf4 wk4 = lwk4[f];
            vf4 wv4 = lwv4[f];
            sc0 += (double)k0v[0] * wk4[0] + (double)k0v[1] * wk4[1]
                 + (double)k0v[2] * wk4[2] + (double)k0v[3] * wk4[3];
            vv0 += (double)k0v[0] * wv4[0] + (double)k0v[1] * wv4[1]
                 + (double)k0v[2] * wv4[2] + (double)k0v[3] * wv4[3];
            sc1 += (double)k1v[0] * wk4[0] + (double)k1v[1] * wk4[1]
                 + (double)k1v[2] * wk4[2] + (double)k1v[3] * wk4[3];
            vv1 += (double)k1v[0] * wv4[0] + (double)k1v[1] * wv4[1]
                 + (double)k1v[2] * wv4[2] + (double)k1v[3] * wv4[3];
            sc2 += (double)k2v[0] * wk4[0] + (double)k2v[1] * wk4[1]
                 + (double)k2v[2] * wk4[2] + (double)k2v[3] * wk4[3];
            vv2 += (double)k2v[0] * wv4[0] + (double)k2v[1] * wv4[1]
                 + (double)k2v[2] * wv4[2] + (double)k2v[3] * wv4[3];
            sc3 += (double)k3v[0] * wk4[0] + (double)k3v[1] * wk4[1]
                 + (double)k3v[2] * wk4[2] + (double)k3v[3] * wk4[3];
            vv3 += (double)k3v[0] * wv4[0] + (double)k3v[1] * wv4[1]
                 + (double)k3v[2] * wv4[2] + (double)k3v[3] * wv4[3];
        }
        #pragma unroll
        for (int off = 32; off > 0; off >>= 1) {
            sc0 += __shfl_down(sc0, off);
            vv0 += __shfl_down(vv0, off);
            sc1 += __shfl_down(sc1, off);
            vv1 += __shfl_down(vv1, off);
            sc2 += __shfl_down(sc2, off);
            vv2 += __shfl_down(vv2, off);
            sc3 += __shfl_down(sc3, off);
            vv3 += __shfl_down(vv3, off);
        }
        if (lane == 0) {
            size_t base = (size_t)b * LK + k;
            scores[base]     = (float)sc0;  vvals[base]     = (float)(vv0 + cv);
            scores[base + 1] = (float)sc1;  vvals[base + 1] = (float)(vv1 + cv);
            scores[base + 2] = (float)sc2;  vvals[base + 2] = (float)(vv2 + cv);
            scores[base + 3] = (float)sc3;  vvals[base + 3] = (float)(vv3 + cv);
        }
    }
}

// =====================================================================
// K5: per-batch softmax + weighted sum -> out[b] (proven round-9)
// =====================================================================
__global__ void __launch_bounds__(256)
k5_softmax(const float* __restrict__ scores, const float* __restrict__ vvals,
           float* __restrict__ out) {
    int b = blockIdx.x;
    int t = threadIdx.x;
    __shared__ float smax_sh[4];
    __shared__ double num_sh[4], den_sh[4];
    const float* sr = scores + (size_t)b * LK;
    const float* vr = vvals  + (size_t)b * LK;
    float m = -INFINITY;
    for (int k = t; k < LK; k += 256) m = fmaxf(m, sr[k]);
    #pragma unroll
    for (int off = 32; off > 0; off >>= 1) m = fmaxf(m, __shfl_down(m, off));
    int w = t >> 6, lane = t & 63;
    if (lane == 0) smax_sh[w] = m;
    __syncthreads();
    float gm = fmaxf(fmaxf(smax_sh[0], smax_sh[1]), fmaxf(smax_sh[2], smax_sh[3]));
    double num = 0.0, den = 0.0;
    for (int k = t; k < LK; k += 256) {
        double e = exp((double)(sr[k] - gm));
        den += e;
        num += e * (double)vr[k];
    }
    #pragma unroll
    for (int off = 32; off > 0; off >>= 1) {
        num += __shfl_down(num, off);
        den += __shfl_down(den, off);
    }
    if (lane == 0) { num_sh[w] = num; den_sh[w] = den; }
    __syncthreads();
    if (t == 0) {
        double N = num_sh[0] + num_sh[1] + num_sh[2] + num_sh[3];
        double D = den_sh[0] + den_sh[1] + den_sh[2] + den_sh[3];
        out[b] = (float)(N / D);
    }
}

extern "C" void kernel_launch(void* const* d_in, const int* in_sizes, int n_in,
                              void* d_out, int out_size, void* d_ws, size_t ws_size,
                              hipStream_t stream) {
    const float* query = (const float*)d_in[0];
    const float* key   = (const float*)d_in[1];
    const float* Wq    = (const float*)d_in[2];
    const float* bq    = (const float*)d_in[3];
    const float* Wk    = (const float*)d_in[4];
    const float* bk    = (const float*)d_in[5];
    const float* Wv    = (const float*)d_in[6];
    const float* bv    = (const float*)d_in[7];
    float* out = (float*)d_out;

    float* ws = (float*)d_ws;
    size_t off = 0;
    float* partial = ws + off; off += (size_t)QCH * NB * HD;   // 8 MB
    float* qsum    = ws + off; off += (size_t)NB * AD;
    float* wk_eff  = ws + off; off += (size_t)NB * HD;
    float* wv_eff  = ws + off; off += (size_t)HD;
    float* c_v     = ws + off; off += 1;
    float* scores  = ws + off; off += (size_t)NB * LK;
    float* vvals   = ws + off; off += (size_t)NB * LK;

    hipLaunchKernelGGL(k1_stream, dim3(NB * QCH + 16 + 1), dim3(256), 0, stream,
                       query, Wk, Wv, bk, bv, partial, wv_eff, c_v);
    hipLaunchKernelGGL(k2_qsum, dim3(256), dim3(256), 0, stream,
                       partial, Wq, bq, qsum);
    hipLaunchKernelGGL(k3_weff, dim3(2048), dim3(256), 0, stream,
                       qsum, Wk, wk_eff);
    hipLaunchKernelGGL(k4_scores, dim3(NB * (LK / 32)), dim3(256), 0, stream,
                       key, wk_eff, wv_eff, c_v, scores, vvals);
    hipLaunchKernelGGL(k5_softmax, dim3(NB), dim3(256), 0, stream,
                       scores, vvals, out);
}